// Round 4
// baseline (1050.275 us; speedup 1.0000x reference)
//
#include <hip/hip_runtime.h>
#include <hip/hip_bf16.h>

typedef unsigned short u16;

#define M_DIM 16384
#define N_DIM 4096
#define K_DIM 4096
#define R_DIM 64
#define BK 64
#define NT_K (K_DIM / BK)   // 64 K-tiles

typedef __bf16 bf16x8 __attribute__((ext_vector_type(8)));
typedef float floatx4 __attribute__((ext_vector_type(4)));
typedef u16 u16x8 __attribute__((ext_vector_type(8)));

__device__ __forceinline__ u16 f2bf(float f) {
    union { float f; unsigned int i; } v;
    v.f = f;
    unsigned int r = v.i + 0x7fffu + ((v.i >> 16) & 1u);  // RNE
    return (u16)(r >> 16);
}

// ---------------------------------------------------------------------------
// Kernel 0: fp32 -> bf16 round-convert (x). Each thread: 8 floats -> 8 bf16.
// ---------------------------------------------------------------------------
__global__ __launch_bounds__(256) void cvt_bf16(const float* __restrict__ in,
                                                u16* __restrict__ out, int n8) {
    int i = blockIdx.x * 256 + threadIdx.x;
    if (i >= n8) return;
    const float4* p = (const float4*)in + (size_t)i * 2;
    float4 a = p[0], b = p[1];
    u16x8 r;
    r[0] = f2bf(a.x); r[1] = f2bf(a.y); r[2] = f2bf(a.z); r[3] = f2bf(a.w);
    r[4] = f2bf(b.x); r[5] = f2bf(b.y); r[6] = f2bf(b.z); r[7] = f2bf(b.w);
    __builtin_nontemporal_store(r, (u16x8*)out + i);
}

// ---------------------------------------------------------------------------
// Kernel 1: fold LoRA into the weight (fp32 in, bf16 out).
// ---------------------------------------------------------------------------
__global__ __launch_bounds__(256) void prep_w(const float* __restrict__ W,
                                              const float* __restrict__ lA,
                                              const float* __restrict__ lB,
                                              u16* __restrict__ Wc) {
    __shared__ float Bs[16][R_DIM];
    const int k = blockIdx.x * 256 + threadIdx.x;
    const int n0 = blockIdx.y * 16;

    for (int i = threadIdx.x; i < 16 * R_DIM; i += 256) {
        int j = i >> 6, r = i & 63;
        Bs[j][r] = lB[(size_t)(n0 + j) * R_DIM + r];
    }
    __syncthreads();

    float acc[16];
#pragma unroll
    for (int j = 0; j < 16; ++j) acc[j] = 0.f;

    for (int r = 0; r < R_DIM; ++r) {
        float a = lA[(size_t)r * K_DIM + k];
#pragma unroll
        for (int j = 0; j < 16; ++j) acc[j] += Bs[j][r] * a;
    }

#pragma unroll
    for (int j = 0; j < 16; ++j) {
        size_t idx = (size_t)(n0 + j) * K_DIM + k;
        Wc[idx] = f2bf(W[idx] + acc[j]);
    }
}

// ---------------------------------------------------------------------------
// Kernel 2: 256x256-tile GEMM, 2-barrier/K-tile schedule (T1..T5).
// C[M][N] = A[M][K](bf16) @ B[N][K](bf16)^T + bias, C f32.
//
// 8 waves (2M x 4N), BK=64, LDS = 2 buf x {A,B} x 2 halves x [128][64] bf16
// = 128 KiB. Per K-tile: stage ALL 4 halves of t+1 at tile top, then two
// super-phases:
//   SP0: Q(0,0)               (reads afA + bfrA = 12 ds_read_b128)
//   SP1: Q(1,0),Q(1,1),Q(0,1) (reads afB + bfrB = 12; 48 MFMAs, no barriers)
// Separate register sets (afA/afB, bfrA/bfrB) so the compiler renames and
// interleaves ds_reads under MFMAs with fine-grained lgkmcnt.
//
// vmcnt ledger (per wave, 2 loads/half, stage order A0,B0,A1,B1):
//   iter top: outstanding = 8 (tile t, staged last iter)
//     vmcnt(4)  -> drains Ah0,Bh0 of t
//     barrier   -> RAW visibility; WAR: all reads of buf^1 (t-1) done
//     stage 8 loads of t+1 into buf^1  (outstanding 12)
//     SP0
//     vmcnt(8)  -> drains Ah1,Bh1 of t; leaves t+1's 8 in flight (never 0)
//     barrier   -> visibility of A1,B1
//     SP1
// Last iter stages a wrapped tile (harmless); drained by final vmcnt(0).
//
// LDS swizzle (G4, round-3-verified conflict-free): row stride = 128 B = 32
// banks, bank-quad = 16B slot. Involution slot' = slot ^ (row&7) on BOTH the
// staging source column and the read offset. SQ_LDS_BANK_CONFLICT == 0.
// ---------------------------------------------------------------------------

#define STAGE_HALF(SB, AB, H, TS) do {                                        \
    const u16* _g = (AB ? gB : gA) +                                          \
        ((size_t)((H) * 128) * K_DIM + (size_t)(TS) * BK);                    \
    __builtin_amdgcn_global_load_lds(                                         \
        (const __attribute__((address_space(1))) void*)_g,                    \
        (__attribute__((address_space(3))) void*)&lds[SB][AB][H][tid * 8],    \
        16, 0, 0);                                                            \
    __builtin_amdgcn_global_load_lds(                                         \
        (const __attribute__((address_space(1))) void*)(_g + (size_t)64 * K_DIM), \
        (__attribute__((address_space(3))) void*)&lds[SB][AB][H][4096 + tid * 8], \
        16, 0, 0);                                                            \
  } while (0)

#define LOAD_AF(DST, BUF, QM) do {                                           \
    const u16* _ba = &lds[BUF][0][QM][0];                                    \
    _Pragma("unroll") for (int mt = 0; mt < 4; ++mt) {                       \
      DST[mt][0] = *(const bf16x8*)(_ba + arow[mt] + koff0);                 \
      DST[mt][1] = *(const bf16x8*)(_ba + arow[mt] + koff1);                 \
    }                                                                        \
  } while (0)

#define LOAD_BF(DST, BUF, QN) do {                                           \
    const u16* _bb = &lds[BUF][1][QN][0];                                    \
    _Pragma("unroll") for (int nt = 0; nt < 2; ++nt) {                       \
      DST[nt][0] = *(const bf16x8*)(_bb + brow[nt] + koff0);                 \
      DST[nt][1] = *(const bf16x8*)(_bb + brow[nt] + koff1);                 \
    }                                                                        \
  } while (0)

#define MFMA16(AF, BF, M0, N0) do {                                          \
    __builtin_amdgcn_s_setprio(1);                                           \
    _Pragma("unroll") for (int mt = 0; mt < 4; ++mt)                         \
      _Pragma("unroll") for (int nt = 0; nt < 2; ++nt)                       \
        _Pragma("unroll") for (int ks = 0; ks < 2; ++ks)                     \
          acc[M0 + mt][N0 + nt] = __builtin_amdgcn_mfma_f32_16x16x32_bf16(   \
              AF[mt][ks], BF[nt][ks], acc[M0 + mt][N0 + nt], 0, 0, 0);       \
    __builtin_amdgcn_s_setprio(0);                                           \
  } while (0)

#define DO_TILE(BUF, TS) do {                                                \
    asm volatile("s_waitcnt vmcnt(4)" ::: "memory");                         \
    __builtin_amdgcn_s_barrier();                                            \
    __builtin_amdgcn_sched_barrier(0);                                       \
    STAGE_HALF((BUF) ^ 1, 0, 0, TS);                                         \
    STAGE_HALF((BUF) ^ 1, 1, 0, TS);                                         \
    STAGE_HALF((BUF) ^ 1, 0, 1, TS);                                         \
    STAGE_HALF((BUF) ^ 1, 1, 1, TS);                                         \
    LOAD_AF(afA, BUF, 0);                                                    \
    LOAD_BF(bfrA, BUF, 0);                                                   \
    MFMA16(afA, bfrA, 0, 0);          /* Q(0,0) */                           \
    asm volatile("s_waitcnt vmcnt(8)" ::: "memory");                         \
    __builtin_amdgcn_s_barrier();                                            \
    __builtin_amdgcn_sched_barrier(0);                                       \
    LOAD_AF(afB, BUF, 1);                                                    \
    LOAD_BF(bfrB, BUF, 1);                                                   \
    MFMA16(afB, bfrA, 4, 0);          /* Q(1,0): B0 still in regs */         \
    MFMA16(afB, bfrB, 4, 2);          /* Q(1,1) */                           \
    MFMA16(afA, bfrB, 0, 2);          /* Q(0,1): regs only */                \
  } while (0)

__global__ __launch_bounds__(512, 2) void gemm_bias(
    const u16* __restrict__ A,      // x bf16 [M][K]
    const u16* __restrict__ B,      // W_comb bf16 [N][K]
    const float* __restrict__ bias, // [N] f32
    float* __restrict__ C) {        // [M][N] f32
    __shared__ __align__(16) u16 lds[2][2][2][8192]; // [buf][A/B][half][128*64]

    const int tid  = threadIdx.x;
    const int lane = tid & 63;
    const int wave = tid >> 6;   // 0..7
    const int wm = wave >> 2;    // 0..1
    const int wn = wave & 3;     // 0..3

    // XCD-bijective swizzle (nwg=1024, %8==0): XCD x gets 2 full bn columns
    // x 64 bm -> its 2 B-panels (4 MB) stay L2-hot.
    const int bid = blockIdx.x;
    const int id2 = (bid & 7) * 128 + (bid >> 3);
    const int bm = id2 & 63;     // 64 M-tiles
    const int bn = id2 >> 6;     // 16 N-tiles
    const int m0 = bm * 256;
    const int n0 = bn * 256;

    // staging: thread t -> rows (t>>3) and 64+(t>>3) of a half, 16B each.
    // Source 16B-slot permuted by slot ^= (row&7): linear LDS dest then holds
    // the swizzled layout (both-sides involution).
    const int srow = tid >> 3;                                    // 0..63
    const int scol = (((tid & 7) ^ ((tid >> 3) & 7)) * 8);        // elems
    const u16* gA = A + (size_t)(m0 + srow) * K_DIM + scol;
    const u16* gB = B + (size_t)(n0 + srow) * K_DIM + scol;

    // fragment read offsets (elems within a [128][64] half, swizzled):
    // row&7 == lane&7 for every fragment row (bases are multiples of 16).
    const int frow = lane & 15;
    const int sw   = (lane & 7) << 3;           // (row&7)*8 elems
    const int k0e  = (lane >> 4) * 8;
    const int koff0 = (k0e) ^ sw;
    const int koff1 = (32 + k0e) ^ sw;
    int arow[4], brow[2];
#pragma unroll
    for (int mt = 0; mt < 4; ++mt) arow[mt] = (wm * 64 + mt * 16 + frow) * 64;
#pragma unroll
    for (int nt = 0; nt < 2; ++nt) brow[nt] = (wn * 32 + nt * 16 + frow) * 64;

    floatx4 acc[8][4];
#pragma unroll
    for (int i = 0; i < 8; ++i)
#pragma unroll
        for (int j = 0; j < 4; ++j) acc[i][j] = (floatx4){0.f, 0.f, 0.f, 0.f};

    bf16x8 afA[4][2], afB[4][2], bfrA[2][2], bfrB[2][2];

    // prologue: stage tile 0 into buf0, order [Ah0, Bh0, Ah1, Bh1]
    STAGE_HALF(0, 0, 0, 0);
    STAGE_HALF(0, 1, 0, 0);
    STAGE_HALF(0, 0, 1, 0);
    STAGE_HALF(0, 1, 1, 0);

    for (int t = 0; t < NT_K; t += 2) {
        DO_TILE(0, t + 1);                  // read buf0, stage t+1 -> buf1
        DO_TILE(1, (t + 2) & (NT_K - 1));   // read buf1, stage t+2 -> buf0
    }
    asm volatile("s_waitcnt vmcnt(0)" ::: "memory"); // drain trailing stages

    // epilogue: C/D layout col = lane&15, row = (lane>>4)*4 + r
    // nontemporal: C is write-once; don't evict L2-resident B panels.
#pragma unroll
    for (int qm = 0; qm < 2; ++qm)
#pragma unroll
    for (int qn = 0; qn < 2; ++qn)
#pragma unroll
    for (int mt = 0; mt < 4; ++mt)
#pragma unroll
    for (int nt = 0; nt < 2; ++nt) {
        const int col = n0 + qn * 128 + wn * 32 + nt * 16 + (lane & 15);
        const float bv = bias[col];
        const int row0 = m0 + qm * 128 + wm * 64 + mt * 16 + ((lane >> 4) << 2);
        floatx4 v = acc[qm * 4 + mt][qn * 2 + nt];
#pragma unroll
        for (int r = 0; r < 4; ++r)
            __builtin_nontemporal_store(v[r] + bv,
                &C[(size_t)(row0 + r) * N_DIM + col]);
    }
}

extern "C" void kernel_launch(void* const* d_in, const int* in_sizes, int n_in,
                              void* d_out, int out_size, void* d_ws, size_t ws_size,
                              hipStream_t stream) {
    const float* x    = (const float*)d_in[0];  // [M][K] f32
    const float* W    = (const float*)d_in[1];  // [N][K] f32
    const float* bias = (const float*)d_in[2];  // [N] f32
    const float* lA   = (const float*)d_in[3];  // [R][K] f32
    const float* lB   = (const float*)d_in[4];  // [N][R] f32
    float* out = (float*)d_out;                 // [M][N] f32

    // workspace: Wc bf16 [N*K] (32 MB), then x_bf16 [M*K] (128 MB)
    u16* Wc = (u16*)d_ws;
    u16* xb = Wc + (size_t)N_DIM * K_DIM;

    cvt_bf16<<<dim3((M_DIM * K_DIM / 8 + 255) / 256), 256, 0, stream>>>(
        x, xb, M_DIM * K_DIM / 8);

    dim3 g1(K_DIM / 256, N_DIM / 16);
    prep_w<<<g1, 256, 0, stream>>>(W, lA, lB, Wc);

    // 64 x 16 = 1024 blocks, 512 threads, 1 block/CU
    gemm_bias<<<dim3(1024), 512, 0, stream>>>(xb, Wc, bias, out);
}